// Round 2
// baseline (254.182 us; speedup 1.0000x reference)
//
#include <hip/hip_runtime.h>
#include <hip/hip_bf16.h>
#include <cstdint>
#include <cstddef>

typedef __bf16 bf16;
typedef __bf16 bf16x4_t __attribute__((ext_vector_type(4)));
typedef __bf16 bf16x8_t __attribute__((ext_vector_type(8)));
typedef float  f32x4_t  __attribute__((ext_vector_type(4)));
typedef unsigned int u32x4_t __attribute__((ext_vector_type(4)));

#define NTOK 4096
#define CH   512
#define SLICE (NTOK*CH)      // 2097152 elements per blade slice
#define WSLICE (CH*CH)       // 262144 elements per weight sub-matrix

// ---------------- convert x: (b,m,i) f32 -> [i][b*512+m] bf16 ----------------
__global__ __launch_bounds__(256) void k_convert_x(const float* __restrict__ x,
                                                   bf16* __restrict__ xb) {
    int p = blockIdx.x * 256 + threadIdx.x;          // 0..SLICE-1
    const f32x4_t* x4 = (const f32x4_t*)x;
    f32x4_t v0 = x4[2*p];
    f32x4_t v1 = x4[2*p+1];
    xb[0*SLICE + p] = (bf16)v0.x;
    xb[1*SLICE + p] = (bf16)v0.y;
    xb[2*SLICE + p] = (bf16)v0.z;
    xb[3*SLICE + p] = (bf16)v0.w;
    xb[4*SLICE + p] = (bf16)v1.x;
    xb[5*SLICE + p] = (bf16)v1.y;
    xb[6*SLICE + p] = (bf16)v1.z;
    xb[7*SLICE + p] = (bf16)v1.w;
}

// ---------------- convert w: (n,m,s) f32 -> [s][n*512+m] bf16 ----------------
__global__ __launch_bounds__(256) void k_convert_w(const float* __restrict__ w,
                                                   bf16* __restrict__ wb) {
    int p = blockIdx.x * 256 + threadIdx.x;          // 0..WSLICE-1
    f32x4_t v = ((const f32x4_t*)w)[p];
    wb[0*WSLICE + p] = (bf16)v.x;
    wb[1*WSLICE + p] = (bf16)v.y;
    wb[2*WSLICE + p] = (bf16)v.z;
    wb[3*WSLICE + p] = (bf16)v.w;
}

// ---------------- GEMM: C[b,n] = sum_m A[b,m] * B[n,m]  (both K-contig) -----
// Tile 128x128, BK=64, 256 threads (4 waves in 2x2), 16x16x32 bf16 MFMA.
// XOR-swizzled LDS (T2): LDS(row, c) holds global chunk c ^ (row&7).
template<int OUTF32>
__global__ __launch_bounds__(256, 2) void k_gemm(const bf16* __restrict__ Abase,
                                                 const bf16* __restrict__ Wbase,
                                                 void* __restrict__ Obase) {
    const int blade = blockIdx.z;
    const int sub = (blade == 0) ? 0 : (blade < 4) ? 1 : (blade < 7) ? 2 : 3;
    const bf16* __restrict__ A = Abase + (size_t)blade * SLICE;
    const bf16* __restrict__ B = Wbase + (size_t)sub * WSLICE;
    const int tm = blockIdx.x * 128, tn = blockIdx.y * 128;

    __shared__ __align__(128) bf16 lsA[128 * 64];
    __shared__ __align__(128) bf16 lsB[128 * 64];
    char* lsAc = (char*)lsA;
    char* lsBc = (char*)lsB;

    const int t = threadIdx.x, lane = t & 63, wid = t >> 6;
    const int waveM = (wid >> 1) * 64, waveN = (wid & 1) * 64;
    const int lrow = lane >> 3;                         // 0..7
    const int srcc = ((lane & 7) ^ lrow) * 8;           // swizzled source k-offset (elements)
    const int xorv = (lane & 7) << 4;                   // read-side XOR (bytes)
    const int kbase = (lane >> 4) * 16;                 // k fragment byte offset in row

    f32x4_t acc[4][4] = {};
    u32x4_t ra[4], rb[4];

    // preload kt=0
    #pragma unroll
    for (int q = 0; q < 4; ++q) {
        int row = wid * 32 + q * 8 + lrow;
        ra[q] = *(const u32x4_t*)(A + (size_t)(tm + row) * CH + srcc);
        rb[q] = *(const u32x4_t*)(B + (size_t)(tn + row) * CH + srcc);
    }

    #pragma unroll 1
    for (int kt = 0; kt < 8; ++kt) {
        __syncthreads();
        #pragma unroll
        for (int q = 0; q < 4; ++q) {
            int row = wid * 32 + q * 8 + lrow;
            *(u32x4_t*)(lsAc + row * 128 + (lane & 7) * 16) = ra[q];
            *(u32x4_t*)(lsBc + row * 128 + (lane & 7) * 16) = rb[q];
        }
        __syncthreads();
        if (kt < 7) {
            const int k0 = (kt + 1) * 64;
            #pragma unroll
            for (int q = 0; q < 4; ++q) {
                int row = wid * 32 + q * 8 + lrow;
                ra[q] = *(const u32x4_t*)(A + (size_t)(tm + row) * CH + k0 + srcc);
                rb[q] = *(const u32x4_t*)(B + (size_t)(tn + row) * CH + k0 + srcc);
            }
        }
        #pragma unroll
        for (int kk = 0; kk < 2; ++kk) {
            bf16x8_t af[4], bv[4];
            #pragma unroll
            for (int mf = 0; mf < 4; ++mf) {
                int row = waveM + mf * 16 + (lane & 15);
                af[mf] = *(const bf16x8_t*)(lsAc + row * 128 + ((kk * 64 + kbase) ^ xorv));
            }
            #pragma unroll
            for (int nf = 0; nf < 4; ++nf) {
                int row = waveN + nf * 16 + (lane & 15);
                bv[nf] = *(const bf16x8_t*)(lsBc + row * 128 + ((kk * 64 + kbase) ^ xorv));
            }
            #pragma unroll
            for (int mf = 0; mf < 4; ++mf)
                #pragma unroll
                for (int nf = 0; nf < 4; ++nf)
                    acc[mf][nf] = __builtin_amdgcn_mfma_f32_16x16x32_bf16(
                        af[mf], bv[nf], acc[mf][nf], 0, 0, 0);
        }
    }

    const int orow0 = tm + waveM + (lane >> 4) * 4;
    const int ocol  = tn + waveN + (lane & 15);
    if constexpr (OUTF32) {
        float* __restrict__ O = (float*)Obase + (size_t)blade * SLICE;
        #pragma unroll
        for (int mf = 0; mf < 4; ++mf)
            #pragma unroll
            for (int r = 0; r < 4; ++r) {
                size_t rowoff = (size_t)(orow0 + mf * 16 + r) * CH;
                #pragma unroll
                for (int nf = 0; nf < 4; ++nf)
                    O[rowoff + ocol + nf * 16] = acc[mf][nf][r];
            }
    } else {
        bf16* __restrict__ O = (bf16*)Obase + (size_t)blade * SLICE;
        #pragma unroll
        for (int mf = 0; mf < 4; ++mf)
            #pragma unroll
            for (int r = 0; r < 4; ++r) {
                size_t rowoff = (size_t)(orow0 + mf * 16 + r) * CH;
                #pragma unroll
                for (int nf = 0; nf < 4; ++nf)
                    O[rowoff + ocol + nf * 16] = (bf16)acc[mf][nf][r];
            }
    }
}

// ---------------- geometric product (elementwise per (b,n)) -----------------
// blade order: masks sorted by (popcount, value): [0,1,2,4,3,5,6,7]
// -> idx<->mask permutation is the transposition 3<->4 (self-inverse).
// sign(a_mask,b_mask) = (-1)^( ((a1^a2)&b0) ^ (a2&b1) )
__global__ __launch_bounds__(256) void k_gp(const bf16* __restrict__ xl,
                                            const bf16* __restrict__ xr,
                                            const float* __restrict__ b1,
                                            const float* __restrict__ b2,
                                            bf16* __restrict__ gp) {
    int p = (blockIdx.x * 256 + threadIdx.x) * 4;
    float l[8][4], r[8][4], g[8][4];
    #pragma unroll
    for (int i = 0; i < 8; ++i) {
        bf16x4_t lv = *(const bf16x4_t*)(xl + (size_t)i * SLICE + p);
        bf16x4_t rv = *(const bf16x4_t*)(xr + (size_t)i * SLICE + p);
        #pragma unroll
        for (int v = 0; v < 4; ++v) { l[i][v] = (float)lv[v]; r[i][v] = (float)rv[v]; g[i][v] = 0.f; }
    }
    int n0 = p & (CH - 1);
    f32x4_t b1v = *(const f32x4_t*)(b1 + n0);
    f32x4_t b2v = *(const f32x4_t*)(b2 + n0);
    #pragma unroll
    for (int v = 0; v < 4; ++v) { l[0][v] += b1v[v]; r[0][v] += b2v[v]; }

    const int IDX[8] = {0, 1, 2, 4, 3, 5, 6, 7};
    #pragma unroll
    for (int a = 0; a < 8; ++a) {
        #pragma unroll
        for (int b = 0; b < 8; ++b) {
            int e = ((((a >> 1) ^ (a >> 2)) & b) & 1) ^ (((a >> 2) & (b >> 1)) & 1);
            int j = IDX[a ^ b], ia = IDX[a], ib = IDX[b];
            #pragma unroll
            for (int v = 0; v < 4; ++v)
                g[j][v] += e ? (-l[ia][v] * r[ib][v]) : (l[ia][v] * r[ib][v]);
        }
    }
    #pragma unroll
    for (int i = 0; i < 8; ++i) {
        bf16x4_t gv;
        #pragma unroll
        for (int v = 0; v < 4; ++v) gv[v] = (bf16)g[i][v];
        *(bf16x4_t*)(gp + (size_t)i * SLICE + p) = gv;
    }
}

// ---------------- layernorm (one block per token) ----------------------------
__global__ __launch_bounds__(256) void k_ln(const float* __restrict__ y,
                                            const float* __restrict__ b3,
                                            const float* __restrict__ an,
                                            float* __restrict__ out) {
    int b = blockIdx.x, t = threadIdx.x;
    float yv[2][8];
    float nsum = 0.f;
    #pragma unroll
    for (int h = 0; h < 2; ++h) {
        int c = t + h * 256;
        size_t base = (size_t)b * CH + c;
        #pragma unroll
        for (int i = 0; i < 8; ++i) yv[h][i] = y[(size_t)i * SLICE + base];
        yv[h][0] += b3[c];
        float q = yv[h][0]*yv[h][0] + yv[h][1]*yv[h][1] + yv[h][2]*yv[h][2] + yv[h][3]*yv[h][3]
                - yv[h][4]*yv[h][4] - yv[h][5]*yv[h][5] - yv[h][6]*yv[h][6] - yv[h][7]*yv[h][7];
        nsum += sqrtf(sqrtf(q * q + 1e-16f));
    }
    #pragma unroll
    for (int off = 32; off; off >>= 1) nsum += __shfl_xor(nsum, off);
    __shared__ float red[4];
    if ((t & 63) == 0) red[t >> 6] = nsum;
    __syncthreads();
    float denom = (red[0] + red[1] + red[2] + red[3]) * (1.f / 512.f) + 1e-6f;
    float inv = 1.f / denom;
    #pragma unroll
    for (int h = 0; h < 2; ++h) {
        int c = t + h * 256;
        float s = an[c] * inv;
        f32x4_t o0, o1;
        o0.x = yv[h][0]*s; o0.y = yv[h][1]*s; o0.z = yv[h][2]*s; o0.w = yv[h][3]*s;
        o1.x = yv[h][4]*s; o1.y = yv[h][5]*s; o1.z = yv[h][6]*s; o1.w = yv[h][7]*s;
        size_t base8 = (size_t)((size_t)b * CH + c) * 8;
        *(f32x4_t*)(out + base8)     = o0;
        *(f32x4_t*)(out + base8 + 4) = o1;
    }
}

extern "C" void kernel_launch(void* const* d_in, const int* in_sizes, int n_in,
                              void* d_out, int out_size, void* d_ws, size_t ws_size,
                              hipStream_t stream) {
    (void)in_sizes; (void)n_in; (void)out_size; (void)ws_size;
    const float* x  = (const float*)d_in[0];
    const float* w1 = (const float*)d_in[1];
    const float* b1 = (const float*)d_in[2];
    const float* w2 = (const float*)d_in[3];
    const float* b2 = (const float*)d_in[4];
    const float* w3 = (const float*)d_in[5];
    const float* b3 = (const float*)d_in[6];
    const float* an = (const float*)d_in[7];

    char* ws = (char*)d_ws;
    // layout: [xb/gp 32MB][xl 32MB | xr 32MB] (reused as y f32 64MB) [w1b 2MB][w2b 2MB][w3b 2MB]
    bf16*  xb  = (bf16*)(ws);
    bf16*  xl  = (bf16*)(ws + 33554432);
    bf16*  xr  = (bf16*)(ws + 67108864);
    float* y   = (float*)(ws + 33554432);
    bf16*  w1b = (bf16*)(ws + 100663296);
    bf16*  w2b = (bf16*)(ws + 102760448);
    bf16*  w3b = (bf16*)(ws + 104857600);

    k_convert_x<<<SLICE / 256, 256, 0, stream>>>(x, xb);
    k_convert_w<<<WSLICE / 256, 256, 0, stream>>>(w1, w1b);
    k_convert_w<<<WSLICE / 256, 256, 0, stream>>>(w2, w2b);
    k_convert_w<<<WSLICE / 256, 256, 0, stream>>>(w3, w3b);

    dim3 gg(NTOK / 128, CH / 128, 8);
    k_gemm<0><<<gg, 256, 0, stream>>>(xb, w1b, (void*)xl);
    k_gemm<0><<<gg, 256, 0, stream>>>(xb, w2b, (void*)xr);
    k_gp<<<SLICE / 4 / 256, 256, 0, stream>>>(xl, xr, b1, b2, xb /* gp overwrites xb */);
    k_gemm<1><<<gg, 256, 0, stream>>>(xb, w3b, (void*)y);
    k_ln<<<NTOK, 256, 0, stream>>>(y, b3, an, (float*)d_out);
}

// Round 3
// 244.603 us; speedup vs baseline: 1.0392x; 1.0392x over previous
//
#include <hip/hip_runtime.h>
#include <hip/hip_bf16.h>
#include <cstdint>
#include <cstddef>

typedef __bf16 bf16;
typedef __bf16 bf16x2_t __attribute__((ext_vector_type(2)));
typedef __bf16 bf16x4_t __attribute__((ext_vector_type(4)));
typedef __bf16 bf16x8_t __attribute__((ext_vector_type(8)));
typedef float  f32x2_t  __attribute__((ext_vector_type(2)));
typedef float  f32x4_t  __attribute__((ext_vector_type(4)));
typedef unsigned int u32x4_t __attribute__((ext_vector_type(4)));

#define NTOK 4096
#define CH   512
#define SLICE (NTOK*CH)      // 2097152 elements per blade slice
#define WSLICE (CH*CH)       // 262144 elements per weight sub-matrix

#define AS1 __attribute__((address_space(1)))
#define AS3 __attribute__((address_space(3)))

__device__ __forceinline__ void gl_lds16(const void* g, void* l) {
    __builtin_amdgcn_global_load_lds((const AS1 unsigned int*)g,
                                     (AS3 unsigned int*)l, 16, 0, 0);
}

// ---------------- convert x: (b,m,i) f32 -> [i][b*512+m] bf16 ----------------
__global__ __launch_bounds__(256) void k_convert_x(const float* __restrict__ x,
                                                   bf16* __restrict__ xb) {
    int p = blockIdx.x * 256 + threadIdx.x;          // 0..SLICE-1
    const f32x4_t* x4 = (const f32x4_t*)x;
    f32x4_t v0 = x4[2*p];
    f32x4_t v1 = x4[2*p+1];
    xb[0*SLICE + p] = (bf16)v0.x;
    xb[1*SLICE + p] = (bf16)v0.y;
    xb[2*SLICE + p] = (bf16)v0.z;
    xb[3*SLICE + p] = (bf16)v0.w;
    xb[4*SLICE + p] = (bf16)v1.x;
    xb[5*SLICE + p] = (bf16)v1.y;
    xb[6*SLICE + p] = (bf16)v1.z;
    xb[7*SLICE + p] = (bf16)v1.w;
}

// -------- convert all 3 weights: (n,m,s) f32 -> [s][n*512+m] bf16 -----------
__global__ __launch_bounds__(256) void k_convert_w(const float* __restrict__ w1,
                                                   const float* __restrict__ w2,
                                                   const float* __restrict__ w3,
                                                   bf16* __restrict__ w1b,
                                                   bf16* __restrict__ w2b,
                                                   bf16* __restrict__ w3b) {
    int p = blockIdx.x * 256 + threadIdx.x;          // 0..WSLICE-1
    const float* w = (blockIdx.y == 0) ? w1 : (blockIdx.y == 1) ? w2 : w3;
    bf16* wb       = (blockIdx.y == 0) ? w1b : (blockIdx.y == 1) ? w2b : w3b;
    f32x4_t v = ((const f32x4_t*)w)[p];
    wb[0*WSLICE + p] = (bf16)v.x;
    wb[1*WSLICE + p] = (bf16)v.y;
    wb[2*WSLICE + p] = (bf16)v.z;
    wb[3*WSLICE + p] = (bf16)v.w;
}

// ---------------- GEMM: C[b,n] = sum_m A[b,m] * B[n,m]  (both K-contig) -----
// Tile 128x128, BK=64, 256 threads (4 waves, 2x2), 16x16x32 bf16 MFMA.
// global_load_lds staging (linear LDS dest, pre-swizzled global source).
// LDS(row, chunk c) holds global chunk c ^ (row&7); read XOR-corrects.
// DUAL=1: one A tile, two B matrices (w1,w2) -> two bf16 outputs.
template<int DUAL>
__global__ __launch_bounds__(256, 2) void k_gemm(const bf16* __restrict__ Abase,
                                                 const bf16* __restrict__ W1base,
                                                 const bf16* __restrict__ W2base,
                                                 bf16* __restrict__ O1base,
                                                 bf16* __restrict__ O2base) {
    const int blade = blockIdx.z;
    const int sub = (blade == 0) ? 0 : (blade < 4) ? 1 : (blade < 7) ? 2 : 3;
    const bf16* A  = Abase + (size_t)blade * SLICE;
    const bf16* B1 = W1base + (size_t)sub * WSLICE;
    const bf16* B2 = W2base + (size_t)sub * WSLICE;
    const int tm = blockIdx.x * 128, tn = blockIdx.y * 128;

    __shared__ __align__(1024) bf16 lsA[128 * 64];
    __shared__ __align__(1024) bf16 lsB1[128 * 64];
    __shared__ __align__(1024) bf16 lsB2[DUAL ? 128 * 64 : 64];
    char* lsAc  = (char*)lsA;
    char* lsB1c = (char*)lsB1;
    char* lsB2c = (char*)lsB2;

    const int t = threadIdx.x, lane = t & 63, wid = t >> 6;
    const int waveM = (wid >> 1) * 64, waveN = (wid & 1) * 64;

    // staging: chunk c = wid*256 + q*64 + lane; row=c>>3, cc=c&7
    const int srow = wid * 32 + (lane >> 3);            // +q*8 per q
    const int sswz = ((lane & 7) ^ (srow & 7)) * 8;     // pre-swizzled k elem off
    const bf16* Ag  = A  + (size_t)(tm + srow) * CH + sswz;
    const bf16* B1g = B1 + (size_t)(tn + srow) * CH + sswz;
    const bf16* B2g = B2 + (size_t)(tn + srow) * CH + sswz;
    const int ldsq = wid * 4096;                        // + q*1024 (bytes)

    // read-side
    const int xorv  = (lane & 7) << 4;                  // byte XOR
    const int kbase = (lane >> 4) * 16;                 // k frag byte off

    f32x4_t accL[4][4] = {};
    f32x4_t accR[4][4] = {};

    #pragma unroll 1
    for (int kt = 0; kt < 8; ++kt) {
        __syncthreads();
        const int k0 = kt * 64;
        #pragma unroll
        for (int q = 0; q < 4; ++q) {
            gl_lds16(Ag  + (size_t)q * 8 * CH + k0, lsAc  + ldsq + q * 1024);
            gl_lds16(B1g + (size_t)q * 8 * CH + k0, lsB1c + ldsq + q * 1024);
            if constexpr (DUAL)
                gl_lds16(B2g + (size_t)q * 8 * CH + k0, lsB2c + ldsq + q * 1024);
        }
        __syncthreads();
        #pragma unroll
        for (int kk = 0; kk < 2; ++kk) {
            const int koff = kk * 64 + kbase;
            bf16x8_t af[4], b1v[4], b2v[4];
            #pragma unroll
            for (int mf = 0; mf < 4; ++mf) {
                int row = waveM + mf * 16 + (lane & 15);
                af[mf] = *(const bf16x8_t*)(lsAc + row * 128 + (koff ^ xorv));
            }
            #pragma unroll
            for (int nf = 0; nf < 4; ++nf) {
                int row = waveN + nf * 16 + (lane & 15);
                b1v[nf] = *(const bf16x8_t*)(lsB1c + row * 128 + (koff ^ xorv));
                if constexpr (DUAL)
                    b2v[nf] = *(const bf16x8_t*)(lsB2c + row * 128 + (koff ^ xorv));
            }
            #pragma unroll
            for (int mf = 0; mf < 4; ++mf)
                #pragma unroll
                for (int nf = 0; nf < 4; ++nf) {
                    accL[mf][nf] = __builtin_amdgcn_mfma_f32_16x16x32_bf16(
                        af[mf], b1v[nf], accL[mf][nf], 0, 0, 0);
                    if constexpr (DUAL)
                        accR[mf][nf] = __builtin_amdgcn_mfma_f32_16x16x32_bf16(
                            af[mf], b2v[nf], accR[mf][nf], 0, 0, 0);
                }
        }
    }

    const int orow0 = tm + waveM + (lane >> 4) * 4;
    const int ocol  = tn + waveN + (lane & 15);
    bf16* O1 = O1base + (size_t)blade * SLICE;
    #pragma unroll
    for (int mf = 0; mf < 4; ++mf)
        #pragma unroll
        for (int r = 0; r < 4; ++r) {
            size_t rowoff = (size_t)(orow0 + mf * 16 + r) * CH;
            #pragma unroll
            for (int nf = 0; nf < 4; ++nf)
                O1[rowoff + ocol + nf * 16] = (bf16)accL[mf][nf][r];
        }
    if constexpr (DUAL) {
        bf16* O2 = O2base + (size_t)blade * SLICE;
        #pragma unroll
        for (int mf = 0; mf < 4; ++mf)
            #pragma unroll
            for (int r = 0; r < 4; ++r) {
                size_t rowoff = (size_t)(orow0 + mf * 16 + r) * CH;
                #pragma unroll
                for (int nf = 0; nf < 4; ++nf)
                    O2[rowoff + ocol + nf * 16] = (bf16)accR[mf][nf][r];
            }
    }
}

// ---------------- geometric product (elementwise per (b,n)) -----------------
// blade order: masks sorted by (popcount, value): [0,1,2,4,3,5,6,7]
// -> idx<->mask permutation is the transposition 3<->4 (self-inverse).
// sign(a_mask,b_mask) = (-1)^( ((a1^a2)&b0) ^ (a2&b1) )
__global__ __launch_bounds__(256) void k_gp(const bf16* __restrict__ xl,
                                            const bf16* __restrict__ xr,
                                            const float* __restrict__ b1,
                                            const float* __restrict__ b2,
                                            bf16* __restrict__ gp) {
    int p = (blockIdx.x * 256 + threadIdx.x) * 4;
    float l[8][4], r[8][4], g[8][4];
    #pragma unroll
    for (int i = 0; i < 8; ++i) {
        bf16x4_t lv = *(const bf16x4_t*)(xl + (size_t)i * SLICE + p);
        bf16x4_t rv = *(const bf16x4_t*)(xr + (size_t)i * SLICE + p);
        #pragma unroll
        for (int v = 0; v < 4; ++v) { l[i][v] = (float)lv[v]; r[i][v] = (float)rv[v]; g[i][v] = 0.f; }
    }
    int n0 = p & (CH - 1);
    f32x4_t b1v = *(const f32x4_t*)(b1 + n0);
    f32x4_t b2v = *(const f32x4_t*)(b2 + n0);
    #pragma unroll
    for (int v = 0; v < 4; ++v) { l[0][v] += b1v[v]; r[0][v] += b2v[v]; }

    const int IDX[8] = {0, 1, 2, 4, 3, 5, 6, 7};
    #pragma unroll
    for (int a = 0; a < 8; ++a) {
        #pragma unroll
        for (int b = 0; b < 8; ++b) {
            int e = ((((a >> 1) ^ (a >> 2)) & b) & 1) ^ (((a >> 2) & (b >> 1)) & 1);
            int j = IDX[a ^ b], ia = IDX[a], ib = IDX[b];
            #pragma unroll
            for (int v = 0; v < 4; ++v)
                g[j][v] += e ? (-l[ia][v] * r[ib][v]) : (l[ia][v] * r[ib][v]);
        }
    }
    #pragma unroll
    for (int i = 0; i < 8; ++i) {
        bf16x4_t gv;
        #pragma unroll
        for (int v = 0; v < 4; ++v) gv[v] = (bf16)g[i][v];
        *(bf16x4_t*)(gp + (size_t)i * SLICE + p) = gv;
    }
}

// ---------------- layernorm (one block per token; y in bf16) -----------------
__global__ __launch_bounds__(256) void k_ln(const bf16* __restrict__ y,
                                            const float* __restrict__ b3,
                                            const float* __restrict__ an,
                                            float* __restrict__ out) {
    int b = blockIdx.x, t = threadIdx.x;
    int c0 = t * 2;
    size_t base = (size_t)b * CH + c0;
    float yv[2][8];
    #pragma unroll
    for (int i = 0; i < 8; ++i) {
        bf16x2_t v = *(const bf16x2_t*)(y + (size_t)i * SLICE + base);
        yv[0][i] = (float)v[0];
        yv[1][i] = (float)v[1];
    }
    f32x2_t b3v = *(const f32x2_t*)(b3 + c0);
    float nsum = 0.f;
    #pragma unroll
    for (int h = 0; h < 2; ++h) {
        yv[h][0] += b3v[h];
        float q = yv[h][0]*yv[h][0] + yv[h][1]*yv[h][1] + yv[h][2]*yv[h][2] + yv[h][3]*yv[h][3]
                - yv[h][4]*yv[h][4] - yv[h][5]*yv[h][5] - yv[h][6]*yv[h][6] - yv[h][7]*yv[h][7];
        nsum += sqrtf(sqrtf(q * q + 1e-16f));
    }
    #pragma unroll
    for (int off = 32; off; off >>= 1) nsum += __shfl_xor(nsum, off);
    __shared__ float red[4];
    if ((t & 63) == 0) red[t >> 6] = nsum;
    __syncthreads();
    float denom = (red[0] + red[1] + red[2] + red[3]) * (1.f / 512.f) + 1e-6f;
    float inv = 1.f / denom;
    f32x2_t anv = *(const f32x2_t*)(an + c0);
    float out16[16];
    #pragma unroll
    for (int h = 0; h < 2; ++h) {
        float s = anv[h] * inv;
        #pragma unroll
        for (int i = 0; i < 8; ++i) out16[h * 8 + i] = yv[h][i] * s;
    }
    size_t base8 = base * 8;
    #pragma unroll
    for (int j = 0; j < 4; ++j)
        *(f32x4_t*)(out + base8 + j * 4) = *(f32x4_t*)(out16 + j * 4);
}

extern "C" void kernel_launch(void* const* d_in, const int* in_sizes, int n_in,
                              void* d_out, int out_size, void* d_ws, size_t ws_size,
                              hipStream_t stream) {
    (void)in_sizes; (void)n_in; (void)out_size; (void)ws_size;
    const float* x  = (const float*)d_in[0];
    const float* w1 = (const float*)d_in[1];
    const float* b1 = (const float*)d_in[2];
    const float* w2 = (const float*)d_in[3];
    const float* b2 = (const float*)d_in[4];
    const float* w3 = (const float*)d_in[5];
    const float* b3 = (const float*)d_in[6];
    const float* an = (const float*)d_in[7];

    char* ws = (char*)d_ws;
    // [xb/gp 32MB][xl 32MB -> y bf16][xr 32MB][w1b 2MB][w2b 2MB][w3b 2MB]
    bf16*  xb  = (bf16*)(ws);
    bf16*  xl  = (bf16*)(ws + 33554432);
    bf16*  xr  = (bf16*)(ws + 67108864);
    bf16*  yb  = (bf16*)(ws + 33554432);   // reuses xl after k_gp consumed it
    bf16*  w1b = (bf16*)(ws + 100663296);
    bf16*  w2b = (bf16*)(ws + 102760448);
    bf16*  w3b = (bf16*)(ws + 104857600);

    k_convert_x<<<SLICE / 256, 256, 0, stream>>>(x, xb);
    dim3 gw(WSLICE / 256, 3);
    k_convert_w<<<gw, 256, 0, stream>>>(w1, w2, w3, w1b, w2b, w3b);

    dim3 gg(NTOK / 128, CH / 128, 8);
    k_gemm<1><<<gg, 256, 0, stream>>>(xb, w1b, w2b, xl, xr);
    k_gp<<<SLICE / 4 / 256, 256, 0, stream>>>(xl, xr, b1, b2, xb /* gp -> xb */);
    k_gemm<0><<<gg, 256, 0, stream>>>(xb, w3b, w3b, yb, yb);
    k_ln<<<NTOK, 256, 0, stream>>>(yb, b3, an, (float*)d_out);
}